// Round 20
// baseline (405.863 us; speedup 1.0000x reference)
//
#include <hip/hip_runtime.h>
#include <math.h>

#define NN 100000
#define EE 1600000
#define NB 1563          // buckets of 64 nodes: ceil(100000/64)

typedef _Float16 f16;
typedef __attribute__((ext_vector_type(2))) _Float16 f16x2;
typedef __attribute__((ext_vector_type(8))) _Float16 f16x8;
typedef __attribute__((ext_vector_type(4))) float f32x4;
typedef unsigned int u32;

__device__ __forceinline__ float frelu(float v){ return v > 0.f ? v : 0.f; }

__device__ __forceinline__ f32x4 mfma16(f16x8 a, f16x8 b, f32x4 c){
    return __builtin_amdgcn_mfma_f32_16x16x32_f16(a, b, c, 0, 0, 0);
}

__device__ __forceinline__ int2 nt_load_int2(const int2* p){
    long long v = __builtin_nontemporal_load((const long long*)p);
    int2 r; r.x = (int)(v & 0xFFFFFFFFll); r.y = (int)(v >> 32);
    return r;
}

// ---------------------------------------------------------------------------
// hist_pack: blocks 0..249 = per-chunk 1563-bin LDS histogram of dst>>6;
// blocks 250..873 = weight packing. totals produced by colscan (no memset).
// ---------------------------------------------------------------------------
__global__ __launch_bounds__(256) void hist_pack(const int* __restrict__ dst,
                                                 int* __restrict__ blockhist,
                                                 const float* __restrict__ W1,
                                                 const float* __restrict__ W2,
                                                 const float* __restrict__ Wrel1,
                                                 const float* __restrict__ Wroot1,
                                                 const float* __restrict__ Wrel2,
                                                 const float* __restrict__ Wroot2,
                                                 const float* __restrict__ Wd1,
                                                 const float* __restrict__ Wd2,
                                                 const float* __restrict__ Wmu,
                                                 const float* __restrict__ Wlv,
                                                 f16* __restrict__ pack)
{
    __shared__ int cntS[NB];
    const int t = threadIdx.x;
    if (blockIdx.x < 250) {
        const int blk = blockIdx.x;
        for (int i = t; i < NB; i += 256) cntS[i] = 0;
        __syncthreads();
        const int ebase = blk * 6400;
        #pragma unroll
        for (int i = 0; i < 25; i++) {
            int k = dst[ebase + i * 256 + t] >> 6;
            atomicAdd(&cntS[k], 1);
        }
        __syncthreads();
        for (int i = t; i < NB; i += 256)
            blockhist[blk * NB + i] = cntS[i];
        return;
    }
    int tt = (blockIdx.x - 250) * 256 + t;    // 624*256 = 159744 exact
    float v;
    if (tt < 32768) {                          // enc1: W1 [256,128], CT=8
        int l = tt;
        int j = l & 7, lane = (l >> 3) & 63, ct = (l >> 9) & 7, kk = l >> 12;
        int k = kk * 32 + ((lane >> 4) << 3) + j, c = (ct << 4) + (lane & 15);
        v = W1[k * 128 + c];
    } else if (tt < 49152) {                   // enc2: W2 [128,128], CT=8
        int l = tt - 32768;
        int j = l & 7, lane = (l >> 3) & 63, ct = (l >> 9) & 7, kk = l >> 12;
        int k = kk * 32 + ((lane >> 4) << 3) + j, c = (ct << 4) + (lane & 15);
        v = W2[k * 128 + c];
    } else if (tt < 81920) {                   // conv1: [Wrel1;Wroot1] K=256, CT=8
        int l = tt - 49152;
        int j = l & 7, lane = (l >> 3) & 63, ct = (l >> 9) & 7, kk = l >> 12;
        int k = kk * 32 + ((lane >> 4) << 3) + j, c = (ct << 4) + (lane & 15);
        v = (k < 128) ? Wrel1[k * 128 + c] : Wroot1[(k - 128) * 128 + c];
    } else if (tt < 114688) {                  // conv2
        int l = tt - 81920;
        int j = l & 7, lane = (l >> 3) & 63, ct = (l >> 9) & 7, kk = l >> 12;
        int k = kk * 32 + ((lane >> 4) << 3) + j, c = (ct << 4) + (lane & 15);
        v = (k < 128) ? Wrel2[k * 128 + c] : Wroot2[(k - 128) * 128 + c];
    } else if (tt < 118784) {                  // dec1: Wd1 [32,128], CT=8, kk=0
        int l = tt - 114688;
        int j = l & 7, lane = (l >> 3) & 63, ct = (l >> 9) & 7;
        int k = ((lane >> 4) << 3) + j, c = (ct << 4) + (lane & 15);
        v = Wd1[k * 128 + c];
    } else if (tt < 151552) {                  // dec2: Wd2 [128,256], CT=16
        int l = tt - 118784;
        int j = l & 7, lane = (l >> 3) & 63, ct = (l >> 9) & 15, kk = l >> 13;
        int k = kk * 32 + ((lane >> 4) << 3) + j, c = (ct << 4) + (lane & 15);
        v = Wd2[k * 256 + c];
    } else {                                  // heads: [Wmu|Wlv] [128,64], CT=4
        int l = tt - 151552;
        int j = l & 7, lane = (l >> 3) & 63, ct = (l >> 9) & 3, kk = l >> 11;
        int k = kk * 32 + ((lane >> 4) << 3) + j, c = (ct << 4) + (lane & 15);
        v = (c < 32) ? Wmu[k * 32 + c] : Wlv[k * 32 + (c - 32)];
    }
    pack[tt] = (f16)v;
}

// ---------------------------------------------------------------------------
// MFMA GEMM building blocks. 64 nodes/block, 4 waves, wave = 16 nodes.
// ---------------------------------------------------------------------------
template<int C>
__device__ __forceinline__ void stage_tile(const float* __restrict__ src, int nbase,
                                           f16* lds, int ldr, int colofs)
{
    const int t = threadIdx.x;
    #pragma unroll
    for (int i = 0; i < (64 * C / 4) / 256; i++) {
        int elem = t + i * 256;
        int row = elem / (C / 4);
        int c4  = elem % (C / 4);
        int srow = nbase + row; if (srow >= NN) srow = NN - 1;
        float4 v = *(const float4*)(src + (size_t)srow * C + c4 * 4);
        union { f16 h[4]; uint2 u; } cv;
        cv.h[0] = (f16)v.x; cv.h[1] = (f16)v.y; cv.h[2] = (f16)v.z; cv.h[3] = (f16)v.w;
        *(uint2*)&lds[row * ldr + colofs + c4 * 4] = cv.u;
    }
}

template<int C>
__device__ __forceinline__ void stage_tile_f16(const f16* __restrict__ src, int nbase,
                                               f16* lds, int ldr, int colofs)
{
    const int t = threadIdx.x;
    #pragma unroll
    for (int i = 0; i < (64 * C / 4) / 256; i++) {
        int elem = t + i * 256;
        int row = elem / (C / 4);
        int c4  = elem % (C / 4);
        int srow = nbase + row; if (srow >= NN) srow = NN - 1;
        uint2 v = *(const uint2*)(src + (size_t)srow * C + c4 * 4);
        *(uint2*)&lds[row * ldr + colofs + c4 * 4] = v;
    }
}

template<int K, int CT>
__device__ __forceinline__ void wave_gemm(const f16* lds, int ldr,
                                          const f16x8* __restrict__ wp, f32x4 acc[CT])
{
    const int lane = threadIdx.x & 63;
    const int wrow = (threadIdx.x >> 6) * 16;
    const int arow = wrow + (lane & 15);
    const int kofs = (lane >> 4) << 3;
    #pragma unroll
    for (int kk = 0; kk < K / 32; kk++) {
        f16x8 a = *(const f16x8*)&lds[arow * ldr + kk * 32 + kofs];
        #pragma unroll
        for (int ct = 0; ct < CT; ct++) {
            f16x8 b = wp[(kk * CT + ct) * 64 + lane];
            acc[ct] = mfma16(a, b, acc[ct]);
        }
    }
}

template<int CT>
__device__ __forceinline__ void zacc(f32x4 acc[CT])
{
    #pragma unroll
    for (int ct = 0; ct < CT; ct++) acc[ct] = f32x4{0.f, 0.f, 0.f, 0.f};
}

// C/D layout (m89): col = lane&15, row = (lane>>4)*4 + reg
template<int CT, bool RELU>
__device__ __forceinline__ void store_f32(float* __restrict__ dst, int OUTC, int nbase,
                                          const float* __restrict__ bias, f32x4 acc[CT])
{
    const int lane = threadIdx.x & 63;
    const int wrow = (threadIdx.x >> 6) * 16;
    #pragma unroll
    for (int ct = 0; ct < CT; ct++) {
        int c = ct * 16 + (lane & 15);
        float bv = bias[c];
        #pragma unroll
        for (int r = 0; r < 4; r++) {
            int node = nbase + wrow + ((lane >> 4) << 2) + r;
            if (node < NN) {
                float v = acc[ct][r] + bv;
                if (RELU) v = frelu(v);
                dst[(size_t)node * OUTC + c] = v;
            }
        }
    }
}

template<int CT, bool RELU>
__device__ __forceinline__ void store_f16g(f16* __restrict__ dst, int OUTC, int nbase,
                                           const float* __restrict__ bias, f32x4 acc[CT])
{
    const int lane = threadIdx.x & 63;
    const int wrow = (threadIdx.x >> 6) * 16;
    #pragma unroll
    for (int ct = 0; ct < CT; ct++) {
        int c = ct * 16 + (lane & 15);
        float bv = bias[c];
        #pragma unroll
        for (int r = 0; r < 4; r++) {
            int node = nbase + wrow + ((lane >> 4) << 2) + r;
            if (node < NN) {
                float v = acc[ct][r] + bv;
                if (RELU) v = frelu(v);
                dst[(size_t)node * OUTC + c] = (f16)v;
            }
        }
    }
}

template<int CT>
__device__ __forceinline__ void store_lds_f16(f16* lds, int ldr,
                                              const float* __restrict__ bias, f32x4 acc[CT])
{
    const int lane = threadIdx.x & 63;
    const int wrow = (threadIdx.x >> 6) * 16;
    #pragma unroll
    for (int ct = 0; ct < CT; ct++) {
        int c = ct * 16 + (lane & 15);
        float bv = bias[c];
        #pragma unroll
        for (int r = 0; r < 4; r++) {
            int row = wrow + ((lane >> 4) << 2) + r;
            lds[row * ldr + c] = (f16)frelu(acc[ct][r] + bv);
        }
    }
}

// ---------------------------------------------------------------------------
// colscan_enc: blocks 0..NB-1 = colscan (exclusive prefixes + totals);
// blocks NB.. = encoder tiles (independent work -> hides enc's serial time).
// ---------------------------------------------------------------------------
__global__ __launch_bounds__(256) void colscan_enc(int* __restrict__ blockhist,
                                                   int* __restrict__ totals,
                                                   const float* __restrict__ x,
                                                   const f16x8* __restrict__ wp1,
                                                   const f16x8* __restrict__ wp2,
                                                   const float* __restrict__ b1,
                                                   const float* __restrict__ b2,
                                                   f16* __restrict__ out)
{
    __shared__ __align__(16) f16 shbuf[64 * 264 + 64 * 136];
    const int t = threadIdx.x;
    if (blockIdx.x < NB) {
        int* lds = (int*)shbuf;
        const int k = blockIdx.x;
        int v = (t < 250) ? blockhist[t * NB + k] : 0;
        lds[t] = v;
        __syncthreads();
        for (int off = 1; off < 256; off <<= 1) {
            int y = (t >= off) ? lds[t - off] : 0;
            __syncthreads();
            lds[t] += y;
            __syncthreads();
        }
        if (t < 250) blockhist[t * NB + k] = lds[t] - v;   // exclusive
        if (t == 255) totals[k] = lds[255];                // bucket total
        return;
    }
    // encoder tile
    f16* xs = shbuf;                 // [64*264]
    f16* h1 = shbuf + 64 * 264;      // [64*136]
    const int nbase = (blockIdx.x - NB) * 64;
    stage_tile<256>(x, nbase, xs, 264, 0);
    __syncthreads();
    f32x4 acc[8];
    zacc<8>(acc);
    wave_gemm<256, 8>(xs, 264, wp1, acc);
    store_lds_f16<8>(h1, 136, b1, acc);
    __syncthreads();
    zacc<8>(acc);
    wave_gemm<128, 8>(h1, 136, wp2, acc);
    store_f16g<8, true>(out, 128, nbase, b2, acc);
}

// ---------------------------------------------------------------------------
// scatter: per-(block,bucket) CONTIGUOUS runs into tmp (R12-verified).
// Record: {src | local<<17, weight_bits}, local = dst & 63.
// ---------------------------------------------------------------------------
__global__ __launch_bounds__(256) void scatter(const int* __restrict__ src,
                                               const int* __restrict__ dst,
                                               const float* __restrict__ ea,
                                               const int* __restrict__ totals,
                                               const int* __restrict__ blockhist,
                                               int* __restrict__ bs_g,
                                               int2* __restrict__ tmp)
{
    __shared__ int bsS[NB + 1];
    __shared__ int tmpS[256];
    __shared__ int carryS;
    __shared__ int prefS[NB];
    __shared__ int cntS[NB];
    const int t = threadIdx.x, blk = blockIdx.x;
    if (t == 0) carryS = 0;
    __syncthreads();
    for (int c = 0; c < 7; c++) {
        int idx = c * 256 + t;
        int val = (idx < NB) ? totals[idx] : 0;
        tmpS[t] = val;
        __syncthreads();
        for (int off = 1; off < 256; off <<= 1) {
            int y = (t >= off) ? tmpS[t - off] : 0;
            __syncthreads();
            tmpS[t] += y;
            __syncthreads();
        }
        if (idx < NB) bsS[idx] = carryS + tmpS[t] - val;
        __syncthreads();
        if (t == 255) carryS += tmpS[255];
        __syncthreads();
    }
    if (t == 0) bsS[NB] = carryS;    // == EE
    for (int i = t; i < NB; i += 256) {
        prefS[i] = blockhist[blk * NB + i];
        cntS[i] = 0;
    }
    __syncthreads();
    if (blk == 0)
        for (int i = t; i < NB + 1; i += 256) bs_g[i] = bsS[i];
    const int ebase = blk * 6400;
    #pragma unroll
    for (int i = 0; i < 25; i++) {
        int e = ebase + i * 256 + t;
        int d = dst[e];
        int k = d >> 6;
        int rank = atomicAdd(&cntS[k], 1);
        int pos = bsS[k] + prefS[k] + rank;
        tmp[pos] = make_int2(src[e] | ((d & 63) << 17), __float_as_int(ea[e]));
    }
}

// ---------------------------------------------------------------------------
// bucket_sort: per-bucket 64-bin counting sort; emits offsets/counts (R12).
// ---------------------------------------------------------------------------
__global__ __launch_bounds__(256) void bucket_sort(const int2* __restrict__ tmp,
                                                   const int* __restrict__ bs_g,
                                                   int2* __restrict__ pairs,
                                                   int* __restrict__ offsets,
                                                   int* __restrict__ counts)
{
    __shared__ int hist[64], excl[64], cursor[64];
    const int t = threadIdx.x, k = blockIdx.x;
    const int start = bs_g[k], end = bs_g[k + 1];
    if (t < 64) hist[t] = 0;
    __syncthreads();
    for (int i = start + t; i < end; i += 256)
        atomicAdd(&hist[(tmp[i].x >> 17) & 63], 1);
    __syncthreads();
    if (t == 0) {
        int run = 0;
        #pragma unroll
        for (int j = 0; j < 64; j++) { excl[j] = run; cursor[j] = run; run += hist[j]; }
    }
    __syncthreads();
    for (int i = start + t; i < end; i += 256) {
        int2 e = tmp[i];
        int local = (e.x >> 17) & 63;
        int rank = atomicAdd(&cursor[local], 1);
        pairs[start + rank] = make_int2(e.x & 0x1FFFF, e.y);
    }
    if (t < 64) {
        int node = (k << 6) + t;
        if (node < NN) {
            counts[node]  = hist[t];
            offsets[node] = start + excl[t] + hist[t];   // END semantics
        }
    }
}

// ---------------------------------------------------------------------------
// agg_conv: fused aggregation + GraphConv combine. One block per 64-node
// bucket. Quarter-wave (16 lanes) gathers 4 nodes' rows (reg accumulate,
// unroll 4 = same MLP as agg_q), writes f16 straight into the conv LDS tile
// (cols 0..128); h tile staged into cols 128..256. Then K=256 MFMA.
// Eliminates the 25.6MB agg write + re-read + one dispatch per layer.
// 33KB LDS -> 4 blocks/CU (R13 occupancy rule respected).
// ---------------------------------------------------------------------------
__global__ __launch_bounds__(256) void agg_conv(const f16* __restrict__ h,
                                                const int2* __restrict__ pairs,
                                                const int* __restrict__ offsets,
                                                const int* __restrict__ counts,
                                                const f16x8* __restrict__ wp,
                                                const float* __restrict__ brel,
                                                f16* __restrict__ out)
{
    __shared__ __align__(16) f16 as_[64 * 264];
    const int nbase = blockIdx.x * 64;
    const int t = threadIdx.x;
    // stage h tile (root term) into cols 128..256
    stage_tile_f16<128>(h, nbase, as_, 264, 128);
    // gather-aggregate into cols 0..128: quarter-slot q handles nodes q*4..q*4+3
    const int q = ((t >> 6) << 2) | ((t & 63) >> 4);   // 0..15
    const int lane16 = t & 15;                          // 16B chunk within row
    const uint4* __restrict__ h16 = (const uint4*)h;
    for (int n = 0; n < 4; n++) {
        const int nl = q * 4 + n;          // local node 0..63
        const int node = nbase + nl;
        int end = 0, i = 0;
        if (node < NN) { end = offsets[node]; i = end - counts[node]; }
        float acc[8];
        #pragma unroll
        for (int j = 0; j < 8; j++) acc[j] = 0.f;
        for (; i + 4 <= end; i += 4) {
            int2 p0 = nt_load_int2(pairs + i);
            int2 p1 = nt_load_int2(pairs + i + 1);
            int2 p2 = nt_load_int2(pairs + i + 2);
            int2 p3 = nt_load_int2(pairs + i + 3);
            uint4 r0 = h16[(size_t)p0.x * 16 + lane16];
            uint4 r1 = h16[(size_t)p1.x * 16 + lane16];
            uint4 r2 = h16[(size_t)p2.x * 16 + lane16];
            uint4 r3 = h16[(size_t)p3.x * 16 + lane16];
            float w0 = __int_as_float(p0.y), w1 = __int_as_float(p1.y);
            float w2 = __int_as_float(p2.y), w3 = __int_as_float(p3.y);
            const f16* e0 = (const f16*)&r0;
            const f16* e1 = (const f16*)&r1;
            const f16* e2 = (const f16*)&r2;
            const f16* e3 = (const f16*)&r3;
            #pragma unroll
            for (int j = 0; j < 8; j++) acc[j] = fmaf(w0, (float)e0[j], acc[j]);
            #pragma unroll
            for (int j = 0; j < 8; j++) acc[j] = fmaf(w1, (float)e1[j], acc[j]);
            #pragma unroll
            for (int j = 0; j < 8; j++) acc[j] = fmaf(w2, (float)e2[j], acc[j]);
            #pragma unroll
            for (int j = 0; j < 8; j++) acc[j] = fmaf(w3, (float)e3[j], acc[j]);
        }
        for (; i < end; ++i) {
            int2 p0 = nt_load_int2(pairs + i);
            uint4 r0 = h16[(size_t)p0.x * 16 + lane16];
            float w0 = __int_as_float(p0.y);
            const f16* e0 = (const f16*)&r0;
            #pragma unroll
            for (int j = 0; j < 8; j++) acc[j] = fmaf(w0, (float)e0[j], acc[j]);
        }
        union { f16 hh[8]; uint4 u; } cv;
        #pragma unroll
        for (int j = 0; j < 8; j++) cv.hh[j] = (f16)acc[j];
        *(uint4*)&as_[nl * 264 + lane16 * 8] = cv.u;
    }
    __syncthreads();
    f32x4 acc8[8];
    zacc<8>(acc8);
    wave_gemm<256, 8>(as_, 264, wp, acc8);
    store_f16g<8, true>(out, 128, nbase, brel, acc8);
}

// ---------------------------------------------------------------------------
// tail2_mfma: heads (MFMA CT=4) + reparam + decoder, LDS-chained (R19, 397us).
// ---------------------------------------------------------------------------
__global__ __launch_bounds__(256) void tail2_mfma(const f16* __restrict__ h,
                                                  const f16x8* __restrict__ wp_hd,
                                                  const float* __restrict__ bmu,
                                                  const float* __restrict__ blv,
                                                  const f16x8* __restrict__ wp_d1,
                                                  const float* __restrict__ bd1,
                                                  const f16x8* __restrict__ wp_d2,
                                                  const float* __restrict__ bd2,
                                                  const float* __restrict__ eps,
                                                  float* __restrict__ out)
{
    __shared__ __align__(16) f16 hsA[64 * 136];     // h staging, reused as hd
    __shared__ __align__(16) float muS[64 * 32];
    __shared__ __align__(16) float lvS[64 * 32];
    __shared__ __align__(16) f16 zf[64 * 40];
    const int nbase = blockIdx.x * 64;
    const int t = threadIdx.x;
    const int lane = t & 63;
    const int wrow = (t >> 6) * 16;

    stage_tile_f16<128>(h, nbase, hsA, 136, 0);
    __syncthreads();

    // --- heads ---
    f32x4 acc4[4];
    zacc<4>(acc4);
    wave_gemm<128, 4>(hsA, 136, wp_hd, acc4);
    #pragma unroll
    for (int ct = 0; ct < 4; ct++) {
        int c = ct * 16 + (lane & 15);
        bool ismu = (c < 32);
        int cc = c & 31;
        float bv = ismu ? bmu[cc] : blv[cc];
        float* gbase = out + (ismu ? (size_t)25600000 : (size_t)28800000);
        float* sb = ismu ? muS : lvS;
        #pragma unroll
        for (int r = 0; r < 4; r++) {
            int row = wrow + ((lane >> 4) << 2) + r;
            int node = nbase + row;
            float v = acc4[ct][r] + bv;
            sb[row * 32 + cc] = v;
            if (node < NN) gbase[(size_t)node * 32 + cc] = v;
        }
    }
    __syncthreads();

    // --- reparam ---
    {
        const int node = t >> 2;             // 0..63
        const int ch0  = (t & 3) * 8;        // 0,8,16,24
        const int gn = nbase + node;
        const float* mu = &muS[node * 32 + ch0];
        const float* lv = &lvS[node * 32 + ch0];
        float4 e0 = make_float4(0.f, 0.f, 0.f, 0.f), e1 = e0;
        if (gn < NN) {
            const size_t g = (size_t)gn * 32 + ch0;
            e0 = *(const float4*)(eps + g);
            e1 = *(const float4*)(eps + g + 4);
        }
        float zv[8];
        zv[0] = fmaf(e0.x, expf(0.5f * lv[0]), mu[0]);
        zv[1] = fmaf(e0.y, expf(0.5f * lv[1]), mu[1]);
        zv[2] = fmaf(e0.z, expf(0.5f * lv[2]), mu[2]);
        zv[3] = fmaf(e0.w, expf(0.5f * lv[3]), mu[3]);
        zv[4] = fmaf(e1.x, expf(0.5f * lv[4]), mu[4]);
        zv[5] = fmaf(e1.y, expf(0.5f * lv[5]), mu[5]);
        zv[6] = fmaf(e1.z, expf(0.5f * lv[6]), mu[6]);
        zv[7] = fmaf(e1.w, expf(0.5f * lv[7]), mu[7]);
        if (gn < NN) {
            const size_t g = (size_t)gn * 32 + ch0;
            *(float4*)(out + 32000000 + g)     = make_float4(zv[0], zv[1], zv[2], zv[3]);
            *(float4*)(out + 32000000 + g + 4) = make_float4(zv[4], zv[5], zv[6], zv[7]);
        }
        #pragma unroll
        for (int j = 0; j < 8; j++) zf[node * 40 + ch0 + j] = (f16)zv[j];
    }
    __syncthreads();

    // --- dec1 ---
    f32x4 acc8[8];
    zacc<8>(acc8);
    wave_gemm<32, 8>(zf, 40, wp_d1, acc8);
    store_lds_f16<8>(hsA, 136, bd1, acc8);
    __syncthreads();

    // --- dec2 ---
    f32x4 acc16[16];
    zacc<16>(acc16);
    wave_gemm<128, 16>(hsA, 136, wp_d2, acc16);
    store_f32<16, false>(out, 256, nbase, bd2, acc16);
}

// ---------------------------------------------------------------------------
extern "C" void kernel_launch(void* const* d_in, const int* in_sizes, int n_in,
                              void* d_out, int out_size, void* d_ws, size_t ws_size,
                              hipStream_t stream)
{
    const float* x     = (const float*)d_in[0];
    const int*   ei    = (const int*)d_in[1];
    const float* ea    = (const float*)d_in[2];
    const float* W1    = (const float*)d_in[3];
    const float* b1    = (const float*)d_in[4];
    const float* W2    = (const float*)d_in[5];
    const float* b2    = (const float*)d_in[6];
    const float* Wrel1 = (const float*)d_in[7];
    const float* brel1 = (const float*)d_in[8];
    const float* Wroot1= (const float*)d_in[9];
    const float* Wrel2 = (const float*)d_in[10];
    const float* brel2 = (const float*)d_in[11];
    const float* Wroot2= (const float*)d_in[12];
    const float* Wmu   = (const float*)d_in[13];
    const float* bmu   = (const float*)d_in[14];
    const float* Wlv   = (const float*)d_in[15];
    const float* blv   = (const float*)d_in[16];
    const float* Wd1   = (const float*)d_in[17];
    const float* bd1   = (const float*)d_in[18];
    const float* Wd2   = (const float*)d_in[19];
    const float* bd2   = (const float*)d_in[20];
    const float* eps   = (const float*)d_in[21];
    float* out = (float*)d_out;

    char* ws = (char*)d_ws;
    int*  totals    = (int*) (ws);                  // [NB]  (pad to 8 KB)
    int*  blockhist = (int*) (ws + 8192);           // [250*NB]     1.56 MB
    int*  bs_g      = (int*) (ws + 1571200);        // [NB+1]
    int2* tmp       = (int2*)(ws + 1577472);        // [E]          12.8 MB
    int2* pairs     = (int2*)(ws + 14377472);       // [E]          12.8 MB
    int*  offsets   = (int*) (ws + 27177472);       // [N]          400 KB
    int*  counts    = (int*) (ws + 27577472);       // [N]          400 KB
    f16*  pack      = (f16*) (ws + 27977472);       // 159744 halves ~319 KB
    // 256B-aligned h buffers (R14/R17 lesson).
    f16*  B0        = (f16*) (ws + 28311552);       // 28311552 = 110592*256
    f16*  B1        = (f16*) (ws + 53911552);       // 53911552 = 210592*256

    const f16x8* wp_enc1  = (const f16x8*)(pack);
    const f16x8* wp_enc2  = (const f16x8*)(pack + 32768);
    const f16x8* wp_conv1 = (const f16x8*)(pack + 49152);
    const f16x8* wp_conv2 = (const f16x8*)(pack + 81920);
    const f16x8* wp_dec1  = (const f16x8*)(pack + 114688);
    const f16x8* wp_dec2  = (const f16x8*)(pack + 118784);
    const f16x8* wp_heads = (const f16x8*)(pack + 151552);

    const int* src = ei;          // edge_index row 0
    const int* dst = ei + EE;     // edge_index row 1

    // --- CSR build + weight packing + encoder (enc hides under colscan) ---
    hist_pack<<<874, 256, 0, stream>>>(dst, blockhist, W1, W2, Wrel1, Wroot1,
                                       Wrel2, Wroot2, Wd1, Wd2, Wmu, Wlv, pack);
    colscan_enc<<<NB + 1563, 256, 0, stream>>>(blockhist, totals, x,
                                               wp_enc1, wp_enc2, b1, b2, B0);
    scatter<<<250, 256, 0, stream>>>(src, dst, ea, totals, blockhist, bs_g, tmp);
    bucket_sort<<<NB, 256, 0, stream>>>(tmp, bs_g, pairs, offsets, counts);

    // --- forward pass: agg fused into conv (6 dispatches total) ---
    agg_conv<<<NB, 256, 0, stream>>>(B0, pairs, offsets, counts, wp_conv1, brel1, B1);
    agg_conv<<<NB, 256, 0, stream>>>(B1, pairs, offsets, counts, wp_conv2, brel2, B0);
    tail2_mfma<<<1563, 256, 0, stream>>>(B0, wp_heads, bmu, blv,
                                         wp_dec1, bd1, wp_dec2, bd2, eps, out);
}

// Round 21
// 385.723 us; speedup vs baseline: 1.0522x; 1.0522x over previous
//
#include <hip/hip_runtime.h>
#include <math.h>

#define NN 100000
#define EE 1600000
#define NB 1563          // buckets of 64 nodes: ceil(100000/64)

typedef _Float16 f16;
typedef __attribute__((ext_vector_type(2))) _Float16 f16x2;
typedef __attribute__((ext_vector_type(8))) _Float16 f16x8;
typedef __attribute__((ext_vector_type(4))) float f32x4;
typedef unsigned int u32;

__device__ __forceinline__ float frelu(float v){ return v > 0.f ? v : 0.f; }

__device__ __forceinline__ f32x4 mfma16(f16x8 a, f16x8 b, f32x4 c){
    return __builtin_amdgcn_mfma_f32_16x16x32_f16(a, b, c, 0, 0, 0);
}

__device__ __forceinline__ int2 nt_load_int2(const int2* p){
    long long v = __builtin_nontemporal_load((const long long*)p);
    int2 r; r.x = (int)(v & 0xFFFFFFFFll); r.y = (int)(v >> 32);
    return r;
}

// ---------------------------------------------------------------------------
// hist_pack: blocks 0..249 = per-chunk 1563-bin LDS histogram of dst>>6;
// blocks 250..873 = weight packing. totals produced by colscan (no memset).
// ---------------------------------------------------------------------------
__global__ __launch_bounds__(256) void hist_pack(const int* __restrict__ dst,
                                                 int* __restrict__ blockhist,
                                                 const float* __restrict__ W1,
                                                 const float* __restrict__ W2,
                                                 const float* __restrict__ Wrel1,
                                                 const float* __restrict__ Wroot1,
                                                 const float* __restrict__ Wrel2,
                                                 const float* __restrict__ Wroot2,
                                                 const float* __restrict__ Wd1,
                                                 const float* __restrict__ Wd2,
                                                 const float* __restrict__ Wmu,
                                                 const float* __restrict__ Wlv,
                                                 f16* __restrict__ pack)
{
    __shared__ int cntS[NB];
    const int t = threadIdx.x;
    if (blockIdx.x < 250) {
        const int blk = blockIdx.x;
        for (int i = t; i < NB; i += 256) cntS[i] = 0;
        __syncthreads();
        const int ebase = blk * 6400;
        #pragma unroll
        for (int i = 0; i < 25; i++) {
            int k = dst[ebase + i * 256 + t] >> 6;
            atomicAdd(&cntS[k], 1);
        }
        __syncthreads();
        for (int i = t; i < NB; i += 256)
            blockhist[blk * NB + i] = cntS[i];
        return;
    }
    int tt = (blockIdx.x - 250) * 256 + t;    // 624*256 = 159744 exact
    float v;
    if (tt < 32768) {                          // enc1: W1 [256,128], CT=8
        int l = tt;
        int j = l & 7, lane = (l >> 3) & 63, ct = (l >> 9) & 7, kk = l >> 12;
        int k = kk * 32 + ((lane >> 4) << 3) + j, c = (ct << 4) + (lane & 15);
        v = W1[k * 128 + c];
    } else if (tt < 49152) {                   // enc2: W2 [128,128], CT=8
        int l = tt - 32768;
        int j = l & 7, lane = (l >> 3) & 63, ct = (l >> 9) & 7, kk = l >> 12;
        int k = kk * 32 + ((lane >> 4) << 3) + j, c = (ct << 4) + (lane & 15);
        v = W2[k * 128 + c];
    } else if (tt < 81920) {                   // conv1: [Wrel1;Wroot1] K=256, CT=8
        int l = tt - 49152;
        int j = l & 7, lane = (l >> 3) & 63, ct = (l >> 9) & 7, kk = l >> 12;
        int k = kk * 32 + ((lane >> 4) << 3) + j, c = (ct << 4) + (lane & 15);
        v = (k < 128) ? Wrel1[k * 128 + c] : Wroot1[(k - 128) * 128 + c];
    } else if (tt < 114688) {                  // conv2
        int l = tt - 81920;
        int j = l & 7, lane = (l >> 3) & 63, ct = (l >> 9) & 7, kk = l >> 12;
        int k = kk * 32 + ((lane >> 4) << 3) + j, c = (ct << 4) + (lane & 15);
        v = (k < 128) ? Wrel2[k * 128 + c] : Wroot2[(k - 128) * 128 + c];
    } else if (tt < 118784) {                  // dec1: Wd1 [32,128], CT=8, kk=0
        int l = tt - 114688;
        int j = l & 7, lane = (l >> 3) & 63, ct = (l >> 9) & 7;
        int k = ((lane >> 4) << 3) + j, c = (ct << 4) + (lane & 15);
        v = Wd1[k * 128 + c];
    } else if (tt < 151552) {                  // dec2: Wd2 [128,256], CT=16
        int l = tt - 118784;
        int j = l & 7, lane = (l >> 3) & 63, ct = (l >> 9) & 15, kk = l >> 13;
        int k = kk * 32 + ((lane >> 4) << 3) + j, c = (ct << 4) + (lane & 15);
        v = Wd2[k * 256 + c];
    } else {                                  // heads: [Wmu|Wlv] [128,64], CT=4
        int l = tt - 151552;
        int j = l & 7, lane = (l >> 3) & 63, ct = (l >> 9) & 3, kk = l >> 11;
        int k = kk * 32 + ((lane >> 4) << 3) + j, c = (ct << 4) + (lane & 15);
        v = (c < 32) ? Wmu[k * 32 + c] : Wlv[k * 32 + (c - 32)];
    }
    pack[tt] = (f16)v;
}

// ---------------------------------------------------------------------------
// MFMA GEMM building blocks. 64 nodes/block, 4 waves, wave = 16 nodes.
// ---------------------------------------------------------------------------
template<int C>
__device__ __forceinline__ void stage_tile(const float* __restrict__ src, int nbase,
                                           f16* lds, int ldr, int colofs)
{
    const int t = threadIdx.x;
    #pragma unroll
    for (int i = 0; i < (64 * C / 4) / 256; i++) {
        int elem = t + i * 256;
        int row = elem / (C / 4);
        int c4  = elem % (C / 4);
        int srow = nbase + row; if (srow >= NN) srow = NN - 1;
        float4 v = *(const float4*)(src + (size_t)srow * C + c4 * 4);
        union { f16 h[4]; uint2 u; } cv;
        cv.h[0] = (f16)v.x; cv.h[1] = (f16)v.y; cv.h[2] = (f16)v.z; cv.h[3] = (f16)v.w;
        *(uint2*)&lds[row * ldr + colofs + c4 * 4] = cv.u;
    }
}

template<int C>
__device__ __forceinline__ void stage_tile_f16(const f16* __restrict__ src, int nbase,
                                               f16* lds, int ldr, int colofs)
{
    const int t = threadIdx.x;
    #pragma unroll
    for (int i = 0; i < (64 * C / 4) / 256; i++) {
        int elem = t + i * 256;
        int row = elem / (C / 4);
        int c4  = elem % (C / 4);
        int srow = nbase + row; if (srow >= NN) srow = NN - 1;
        uint2 v = *(const uint2*)(src + (size_t)srow * C + c4 * 4);
        *(uint2*)&lds[row * ldr + colofs + c4 * 4] = v;
    }
}

template<int K, int CT>
__device__ __forceinline__ void wave_gemm(const f16* lds, int ldr,
                                          const f16x8* __restrict__ wp, f32x4 acc[CT])
{
    const int lane = threadIdx.x & 63;
    const int wrow = (threadIdx.x >> 6) * 16;
    const int arow = wrow + (lane & 15);
    const int kofs = (lane >> 4) << 3;
    #pragma unroll
    for (int kk = 0; kk < K / 32; kk++) {
        f16x8 a = *(const f16x8*)&lds[arow * ldr + kk * 32 + kofs];
        #pragma unroll
        for (int ct = 0; ct < CT; ct++) {
            f16x8 b = wp[(kk * CT + ct) * 64 + lane];
            acc[ct] = mfma16(a, b, acc[ct]);
        }
    }
}

template<int CT>
__device__ __forceinline__ void zacc(f32x4 acc[CT])
{
    #pragma unroll
    for (int ct = 0; ct < CT; ct++) acc[ct] = f32x4{0.f, 0.f, 0.f, 0.f};
}

// C/D layout (m89): col = lane&15, row = (lane>>4)*4 + reg
template<int CT, bool RELU>
__device__ __forceinline__ void store_f32(float* __restrict__ dst, int OUTC, int nbase,
                                          const float* __restrict__ bias, f32x4 acc[CT])
{
    const int lane = threadIdx.x & 63;
    const int wrow = (threadIdx.x >> 6) * 16;
    #pragma unroll
    for (int ct = 0; ct < CT; ct++) {
        int c = ct * 16 + (lane & 15);
        float bv = bias[c];
        #pragma unroll
        for (int r = 0; r < 4; r++) {
            int node = nbase + wrow + ((lane >> 4) << 2) + r;
            if (node < NN) {
                float v = acc[ct][r] + bv;
                if (RELU) v = frelu(v);
                dst[(size_t)node * OUTC + c] = v;
            }
        }
    }
}

template<int CT, bool RELU>
__device__ __forceinline__ void store_f16g(f16* __restrict__ dst, int OUTC, int nbase,
                                           const float* __restrict__ bias, f32x4 acc[CT])
{
    const int lane = threadIdx.x & 63;
    const int wrow = (threadIdx.x >> 6) * 16;
    #pragma unroll
    for (int ct = 0; ct < CT; ct++) {
        int c = ct * 16 + (lane & 15);
        float bv = bias[c];
        #pragma unroll
        for (int r = 0; r < 4; r++) {
            int node = nbase + wrow + ((lane >> 4) << 2) + r;
            if (node < NN) {
                float v = acc[ct][r] + bv;
                if (RELU) v = frelu(v);
                dst[(size_t)node * OUTC + c] = (f16)v;
            }
        }
    }
}

template<int CT>
__device__ __forceinline__ void store_lds_f16(f16* lds, int ldr,
                                              const float* __restrict__ bias, f32x4 acc[CT])
{
    const int lane = threadIdx.x & 63;
    const int wrow = (threadIdx.x >> 6) * 16;
    #pragma unroll
    for (int ct = 0; ct < CT; ct++) {
        int c = ct * 16 + (lane & 15);
        float bv = bias[c];
        #pragma unroll
        for (int r = 0; r < 4; r++) {
            int row = wrow + ((lane >> 4) << 2) + r;
            lds[row * ldr + c] = (f16)frelu(acc[ct][r] + bv);
        }
    }
}

// ---------------------------------------------------------------------------
// colscan_enc: blocks 0..NB-1 = colscan (exclusive prefixes + totals);
// blocks NB.. = encoder tiles (independent work -> hides enc's serial time).
// ---------------------------------------------------------------------------
__global__ __launch_bounds__(256) void colscan_enc(int* __restrict__ blockhist,
                                                   int* __restrict__ totals,
                                                   const float* __restrict__ x,
                                                   const f16x8* __restrict__ wp1,
                                                   const f16x8* __restrict__ wp2,
                                                   const float* __restrict__ b1,
                                                   const float* __restrict__ b2,
                                                   f16* __restrict__ out)
{
    __shared__ __align__(16) f16 shbuf[64 * 264 + 64 * 136];
    const int t = threadIdx.x;
    if (blockIdx.x < NB) {
        int* lds = (int*)shbuf;
        const int k = blockIdx.x;
        int v = (t < 250) ? blockhist[t * NB + k] : 0;
        lds[t] = v;
        __syncthreads();
        for (int off = 1; off < 256; off <<= 1) {
            int y = (t >= off) ? lds[t - off] : 0;
            __syncthreads();
            lds[t] += y;
            __syncthreads();
        }
        if (t < 250) blockhist[t * NB + k] = lds[t] - v;   // exclusive
        if (t == 255) totals[k] = lds[255];                // bucket total
        return;
    }
    // encoder tile
    f16* xs = shbuf;                 // [64*264]
    f16* h1 = shbuf + 64 * 264;      // [64*136]
    const int nbase = (blockIdx.x - NB) * 64;
    stage_tile<256>(x, nbase, xs, 264, 0);
    __syncthreads();
    f32x4 acc[8];
    zacc<8>(acc);
    wave_gemm<256, 8>(xs, 264, wp1, acc);
    store_lds_f16<8>(h1, 136, b1, acc);
    __syncthreads();
    zacc<8>(acc);
    wave_gemm<128, 8>(h1, 136, wp2, acc);
    store_f16g<8, true>(out, 128, nbase, b2, acc);
}

// ---------------------------------------------------------------------------
// scatter: per-(block,bucket) CONTIGUOUS runs into tmp (R12-verified).
// Record: {src | local<<17, weight_bits}, local = dst & 63.
// ---------------------------------------------------------------------------
__global__ __launch_bounds__(256) void scatter(const int* __restrict__ src,
                                               const int* __restrict__ dst,
                                               const float* __restrict__ ea,
                                               const int* __restrict__ totals,
                                               const int* __restrict__ blockhist,
                                               int* __restrict__ bs_g,
                                               int2* __restrict__ tmp)
{
    __shared__ int bsS[NB + 1];
    __shared__ int tmpS[256];
    __shared__ int carryS;
    __shared__ int prefS[NB];
    __shared__ int cntS[NB];
    const int t = threadIdx.x, blk = blockIdx.x;
    if (t == 0) carryS = 0;
    __syncthreads();
    for (int c = 0; c < 7; c++) {
        int idx = c * 256 + t;
        int val = (idx < NB) ? totals[idx] : 0;
        tmpS[t] = val;
        __syncthreads();
        for (int off = 1; off < 256; off <<= 1) {
            int y = (t >= off) ? tmpS[t - off] : 0;
            __syncthreads();
            tmpS[t] += y;
            __syncthreads();
        }
        if (idx < NB) bsS[idx] = carryS + tmpS[t] - val;
        __syncthreads();
        if (t == 255) carryS += tmpS[255];
        __syncthreads();
    }
    if (t == 0) bsS[NB] = carryS;    // == EE
    for (int i = t; i < NB; i += 256) {
        prefS[i] = blockhist[blk * NB + i];
        cntS[i] = 0;
    }
    __syncthreads();
    if (blk == 0)
        for (int i = t; i < NB + 1; i += 256) bs_g[i] = bsS[i];
    const int ebase = blk * 6400;
    #pragma unroll
    for (int i = 0; i < 25; i++) {
        int e = ebase + i * 256 + t;
        int d = dst[e];
        int k = d >> 6;
        int rank = atomicAdd(&cntS[k], 1);
        int pos = bsS[k] + prefS[k] + rank;
        tmp[pos] = make_int2(src[e] | ((d & 63) << 17), __float_as_int(ea[e]));
    }
}

// ---------------------------------------------------------------------------
// bucket_sort: per-bucket 64-bin counting sort; emits offsets/counts (R12).
// ---------------------------------------------------------------------------
__global__ __launch_bounds__(256) void bucket_sort(const int2* __restrict__ tmp,
                                                   const int* __restrict__ bs_g,
                                                   int2* __restrict__ pairs,
                                                   int* __restrict__ offsets,
                                                   int* __restrict__ counts)
{
    __shared__ int hist[64], excl[64], cursor[64];
    const int t = threadIdx.x, k = blockIdx.x;
    const int start = bs_g[k], end = bs_g[k + 1];
    if (t < 64) hist[t] = 0;
    __syncthreads();
    for (int i = start + t; i < end; i += 256)
        atomicAdd(&hist[(tmp[i].x >> 17) & 63], 1);
    __syncthreads();
    if (t == 0) {
        int run = 0;
        #pragma unroll
        for (int j = 0; j < 64; j++) { excl[j] = run; cursor[j] = run; run += hist[j]; }
    }
    __syncthreads();
    for (int i = start + t; i < end; i += 256) {
        int2 e = tmp[i];
        int local = (e.x >> 17) & 63;
        int rank = atomicAdd(&cursor[local], 1);
        pairs[start + rank] = make_int2(e.x & 0x1FFFF, e.y);
    }
    if (t < 64) {
        int node = (k << 6) + t;
        if (node < NN) {
            counts[node]  = hist[t];
            offsets[node] = start + excl[t] + hist[t];   // END semantics
        }
    }
}

// ---------------------------------------------------------------------------
// Aggregation: quarter-wave (16 lanes x 16B) per node, UNROLL 8 (VGPR
// headroom confirmed at unroll 4; 8 rows in flight pushes gather MLP).
// ---------------------------------------------------------------------------
__global__ __launch_bounds__(256) void agg_q(const f16* __restrict__ h,
                                             const int2* __restrict__ pairs,
                                             const int* __restrict__ offsets,
                                             const int* __restrict__ counts,
                                             f16* __restrict__ out)
{
    const int gt   = blockIdx.x * 256 + threadIdx.x;   // grid exact: 6250*256
    const int node = gt >> 4;                          // 100000 nodes
    const int ch   = gt & 15;                          // 16B chunk within row
    const int end  = offsets[node];
    int i = end - counts[node];
    float acc[8];
    #pragma unroll
    for (int j = 0; j < 8; j++) acc[j] = 0.f;
    const uint4* __restrict__ h16 = (const uint4*)h;   // 16 chunks per row
    for (; i + 8 <= end; i += 8) {
        int2 p[8];
        uint4 r[8];
        #pragma unroll
        for (int u = 0; u < 8; u++) p[u] = nt_load_int2(pairs + i + u);
        #pragma unroll
        for (int u = 0; u < 8; u++) r[u] = h16[(size_t)p[u].x * 16 + ch];
        #pragma unroll
        for (int u = 0; u < 8; u++) {
            float w = __int_as_float(p[u].y);
            const f16* e = (const f16*)&r[u];
            #pragma unroll
            for (int j = 0; j < 8; j++) acc[j] = fmaf(w, (float)e[j], acc[j]);
        }
    }
    for (; i + 4 <= end; i += 4) {
        int2 p0 = nt_load_int2(pairs + i);
        int2 p1 = nt_load_int2(pairs + i + 1);
        int2 p2 = nt_load_int2(pairs + i + 2);
        int2 p3 = nt_load_int2(pairs + i + 3);
        uint4 r0 = h16[(size_t)p0.x * 16 + ch];
        uint4 r1 = h16[(size_t)p1.x * 16 + ch];
        uint4 r2 = h16[(size_t)p2.x * 16 + ch];
        uint4 r3 = h16[(size_t)p3.x * 16 + ch];
        float w0 = __int_as_float(p0.y), w1 = __int_as_float(p1.y);
        float w2 = __int_as_float(p2.y), w3 = __int_as_float(p3.y);
        const f16* e0 = (const f16*)&r0;
        const f16* e1 = (const f16*)&r1;
        const f16* e2 = (const f16*)&r2;
        const f16* e3 = (const f16*)&r3;
        #pragma unroll
        for (int j = 0; j < 8; j++) acc[j] = fmaf(w0, (float)e0[j], acc[j]);
        #pragma unroll
        for (int j = 0; j < 8; j++) acc[j] = fmaf(w1, (float)e1[j], acc[j]);
        #pragma unroll
        for (int j = 0; j < 8; j++) acc[j] = fmaf(w2, (float)e2[j], acc[j]);
        #pragma unroll
        for (int j = 0; j < 8; j++) acc[j] = fmaf(w3, (float)e3[j], acc[j]);
    }
    for (; i < end; ++i) {
        int2 p0 = nt_load_int2(pairs + i);
        uint4 r0 = h16[(size_t)p0.x * 16 + ch];
        float w0 = __int_as_float(p0.y);
        const f16* e0 = (const f16*)&r0;
        #pragma unroll
        for (int j = 0; j < 8; j++) acc[j] = fmaf(w0, (float)e0[j], acc[j]);
    }
    union { f16 hh[8]; uint4 u; } cv;
    #pragma unroll
    for (int j = 0; j < 8; j++) cv.hh[j] = (f16)acc[j];
    ((uint4*)out)[(size_t)node * 16 + ch] = cv.u;
}

// ---------------------------------------------------------------------------
// GraphConv combine: out = relu([agg|h]@[Wrel;Wroot]+brel), fp16 in/out.
// ---------------------------------------------------------------------------
__global__ __launch_bounds__(256) void conv_mfma(const f16* __restrict__ agg,
                                                 const f16* __restrict__ h,
                                                 const f16x8* __restrict__ wp,
                                                 const float* __restrict__ brel,
                                                 f16* __restrict__ out)
{
    __shared__ __align__(16) f16 as_[64 * 264];
    const int nbase = blockIdx.x * 64;
    stage_tile_f16<128>(agg, nbase, as_, 264, 0);
    stage_tile_f16<128>(h,   nbase, as_, 264, 128);
    __syncthreads();
    f32x4 acc[8];
    zacc<8>(acc);
    wave_gemm<256, 8>(as_, 264, wp, acc);
    store_f16g<8, true>(out, 128, nbase, brel, acc);
}

// ---------------------------------------------------------------------------
// tail2_mfma: heads (MFMA CT=4) + reparam + decoder, LDS-chained (R19, 397us).
// ---------------------------------------------------------------------------
__global__ __launch_bounds__(256) void tail2_mfma(const f16* __restrict__ h,
                                                  const f16x8* __restrict__ wp_hd,
                                                  const float* __restrict__ bmu,
                                                  const float* __restrict__ blv,
                                                  const f16x8* __restrict__ wp_d1,
                                                  const float* __restrict__ bd1,
                                                  const f16x8* __restrict__ wp_d2,
                                                  const float* __restrict__ bd2,
                                                  const float* __restrict__ eps,
                                                  float* __restrict__ out)
{
    __shared__ __align__(16) f16 hsA[64 * 136];     // h staging, reused as hd
    __shared__ __align__(16) float muS[64 * 32];
    __shared__ __align__(16) float lvS[64 * 32];
    __shared__ __align__(16) f16 zf[64 * 40];
    const int nbase = blockIdx.x * 64;
    const int t = threadIdx.x;
    const int lane = t & 63;
    const int wrow = (t >> 6) * 16;

    stage_tile_f16<128>(h, nbase, hsA, 136, 0);
    __syncthreads();

    // --- heads ---
    f32x4 acc4[4];
    zacc<4>(acc4);
    wave_gemm<128, 4>(hsA, 136, wp_hd, acc4);
    #pragma unroll
    for (int ct = 0; ct < 4; ct++) {
        int c = ct * 16 + (lane & 15);
        bool ismu = (c < 32);
        int cc = c & 31;
        float bv = ismu ? bmu[cc] : blv[cc];
        float* gbase = out + (ismu ? (size_t)25600000 : (size_t)28800000);
        float* sb = ismu ? muS : lvS;
        #pragma unroll
        for (int r = 0; r < 4; r++) {
            int row = wrow + ((lane >> 4) << 2) + r;
            int node = nbase + row;
            float v = acc4[ct][r] + bv;
            sb[row * 32 + cc] = v;
            if (node < NN) gbase[(size_t)node * 32 + cc] = v;
        }
    }
    __syncthreads();

    // --- reparam ---
    {
        const int node = t >> 2;             // 0..63
        const int ch0  = (t & 3) * 8;        // 0,8,16,24
        const int gn = nbase + node;
        const float* mu = &muS[node * 32 + ch0];
        const float* lv = &lvS[node * 32 + ch0];
        float4 e0 = make_float4(0.f, 0.f, 0.f, 0.f), e1 = e0;
        if (gn < NN) {
            const size_t g = (size_t)gn * 32 + ch0;
            e0 = *(const float4*)(eps + g);
            e1 = *(const float4*)(eps + g + 4);
        }
        float zv[8];
        zv[0] = fmaf(e0.x, expf(0.5f * lv[0]), mu[0]);
        zv[1] = fmaf(e0.y, expf(0.5f * lv[1]), mu[1]);
        zv[2] = fmaf(e0.z, expf(0.5f * lv[2]), mu[2]);
        zv[3] = fmaf(e0.w, expf(0.5f * lv[3]), mu[3]);
        zv[4] = fmaf(e1.x, expf(0.5f * lv[4]), mu[4]);
        zv[5] = fmaf(e1.y, expf(0.5f * lv[5]), mu[5]);
        zv[6] = fmaf(e1.z, expf(0.5f * lv[6]), mu[6]);
        zv[7] = fmaf(e1.w, expf(0.5f * lv[7]), mu[7]);
        if (gn < NN) {
            const size_t g = (size_t)gn * 32 + ch0;
            *(float4*)(out + 32000000 + g)     = make_float4(zv[0], zv[1], zv[2], zv[3]);
            *(float4*)(out + 32000000 + g + 4) = make_float4(zv[4], zv[5], zv[6], zv[7]);
        }
        #pragma unroll
        for (int j = 0; j < 8; j++) zf[node * 40 + ch0 + j] = (f16)zv[j];
    }
    __syncthreads();

    // --- dec1 ---
    f32x4 acc8[8];
    zacc<8>(acc8);
    wave_gemm<32, 8>(zf, 40, wp_d1, acc8);
    store_lds_f16<8>(hsA, 136, bd1, acc8);
    __syncthreads();

    // --- dec2 ---
    f32x4 acc16[16];
    zacc<16>(acc16);
    wave_gemm<128, 16>(hsA, 136, wp_d2, acc16);
    store_f32<16, false>(out, 256, nbase, bd2, acc16);
}

// ---------------------------------------------------------------------------
extern "C" void kernel_launch(void* const* d_in, const int* in_sizes, int n_in,
                              void* d_out, int out_size, void* d_ws, size_t ws_size,
                              hipStream_t stream)
{
    const float* x     = (const float*)d_in[0];
    const int*   ei    = (const int*)d_in[1];
    const float* ea    = (const float*)d_in[2];
    const float* W1    = (const float*)d_in[3];
    const float* b1    = (const float*)d_in[4];
    const float* W2    = (const float*)d_in[5];
    const float* b2    = (const float*)d_in[6];
    const float* Wrel1 = (const float*)d_in[7];
    const float* brel1 = (const float*)d_in[8];
    const float* Wroot1= (const float*)d_in[9];
    const float* Wrel2 = (const float*)d_in[10];
    const float* brel2 = (const float*)d_in[11];
    const float* Wroot2= (const float*)d_in[12];
    const float* Wmu   = (const float*)d_in[13];
    const float* bmu   = (const float*)d_in[14];
    const float* Wlv   = (const float*)d_in[15];
    const float* blv   = (const float*)d_in[16];
    const float* Wd1   = (const float*)d_in[17];
    const float* bd1   = (const float*)d_in[18];
    const float* Wd2   = (const float*)d_in[19];
    const float* bd2   = (const float*)d_in[20];
    const float* eps   = (const float*)d_in[21];
    float* out = (float*)d_out;

    char* ws = (char*)d_ws;
    int*  totals    = (int*) (ws);                  // [NB]  (pad to 8 KB)
    int*  blockhist = (int*) (ws + 8192);           // [250*NB]     1.56 MB
    int*  bs_g      = (int*) (ws + 1571200);        // [NB+1]
    int2* tmp       = (int2*)(ws + 1577472);        // [E]          12.8 MB
    int2* pairs     = (int2*)(ws + 14377472);       // [E]          12.8 MB
    int*  offsets   = (int*) (ws + 27177472);       // [N]          400 KB
    int*  counts    = (int*) (ws + 27577472);       // [N]          400 KB
    f16*  pack      = (f16*) (ws + 27977472);       // 159744 halves ~319 KB
    // 256B-aligned h buffers (R14/R17 lesson).
    f16*  B0        = (f16*) (ws + 28311552);       // 28311552 = 110592*256
    f16*  B1        = (f16*) (ws + 53911552);       // 53911552 = 210592*256

    const f16x8* wp_enc1  = (const f16x8*)(pack);
    const f16x8* wp_enc2  = (const f16x8*)(pack + 32768);
    const f16x8* wp_conv1 = (const f16x8*)(pack + 49152);
    const f16x8* wp_conv2 = (const f16x8*)(pack + 81920);
    const f16x8* wp_dec1  = (const f16x8*)(pack + 114688);
    const f16x8* wp_dec2  = (const f16x8*)(pack + 118784);
    const f16x8* wp_heads = (const f16x8*)(pack + 151552);

    const int* src = ei;          // edge_index row 0
    const int* dst = ei + EE;     // edge_index row 1

    // --- CSR build + weight packing + encoder (enc hides under colscan) ---
    hist_pack<<<874, 256, 0, stream>>>(dst, blockhist, W1, W2, Wrel1, Wroot1,
                                       Wrel2, Wroot2, Wd1, Wd2, Wmu, Wlv, pack);
    colscan_enc<<<NB + 1563, 256, 0, stream>>>(blockhist, totals, x,
                                               wp_enc1, wp_enc2, b1, b2, B0);
    scatter<<<250, 256, 0, stream>>>(src, dst, ea, totals, blockhist, bs_g, tmp);
    bucket_sort<<<NB, 256, 0, stream>>>(tmp, bs_g, pairs, offsets, counts);

    // --- forward pass: 8 dispatches total ---
    agg_q<<<6250, 256, 0, stream>>>(B0, pairs, offsets, counts, B1);
    conv_mfma<<<1563, 256, 0, stream>>>(B1, B0, wp_conv1, brel1, B1);
    agg_q<<<6250, 256, 0, stream>>>(B1, pairs, offsets, counts, B0);
    conv_mfma<<<1563, 256, 0, stream>>>(B0, B1, wp_conv2, brel2, B0);
    tail2_mfma<<<1563, 256, 0, stream>>>(B0, wp_heads, bmu, blv,
                                         wp_dec1, bd1, wp_dec2, bd2, eps, out);
}

// Round 22
// 375.882 us; speedup vs baseline: 1.0798x; 1.0262x over previous
//
#include <hip/hip_runtime.h>
#include <math.h>

#define NN 100000
#define EE 1600000
#define NB 1563          // buckets of 64 nodes: ceil(100000/64)
#define NCB 98           // colscan blocks: ceil(NB/16)

typedef _Float16 f16;
typedef __attribute__((ext_vector_type(2))) _Float16 f16x2;
typedef __attribute__((ext_vector_type(8))) _Float16 f16x8;
typedef __attribute__((ext_vector_type(4))) float f32x4;
typedef unsigned int u32;

__device__ __forceinline__ float frelu(float v){ return v > 0.f ? v : 0.f; }

__device__ __forceinline__ f32x4 mfma16(f16x8 a, f16x8 b, f32x4 c){
    return __builtin_amdgcn_mfma_f32_16x16x32_f16(a, b, c, 0, 0, 0);
}

__device__ __forceinline__ int2 nt_load_int2(const int2* p){
    long long v = __builtin_nontemporal_load((const long long*)p);
    int2 r; r.x = (int)(v & 0xFFFFFFFFll); r.y = (int)(v >> 32);
    return r;
}

// ---------------------------------------------------------------------------
// hist_pack: blocks 0..249 = per-chunk 1563-bin LDS histogram of dst>>6;
// blocks 250..873 = weight packing. totals produced by colscan (no memset).
// ---------------------------------------------------------------------------
__global__ __launch_bounds__(256) void hist_pack(const int* __restrict__ dst,
                                                 int* __restrict__ blockhist,
                                                 const float* __restrict__ W1,
                                                 const float* __restrict__ W2,
                                                 const float* __restrict__ Wrel1,
                                                 const float* __restrict__ Wroot1,
                                                 const float* __restrict__ Wrel2,
                                                 const float* __restrict__ Wroot2,
                                                 const float* __restrict__ Wd1,
                                                 const float* __restrict__ Wd2,
                                                 const float* __restrict__ Wmu,
                                                 const float* __restrict__ Wlv,
                                                 f16* __restrict__ pack)
{
    __shared__ int cntS[NB];
    const int t = threadIdx.x;
    if (blockIdx.x < 250) {
        const int blk = blockIdx.x;
        for (int i = t; i < NB; i += 256) cntS[i] = 0;
        __syncthreads();
        const int ebase = blk * 6400;
        #pragma unroll
        for (int i = 0; i < 25; i++) {
            int k = dst[ebase + i * 256 + t] >> 6;
            atomicAdd(&cntS[k], 1);
        }
        __syncthreads();
        for (int i = t; i < NB; i += 256)
            blockhist[blk * NB + i] = cntS[i];
        return;
    }
    int tt = (blockIdx.x - 250) * 256 + t;    // 624*256 = 159744 exact
    float v;
    if (tt < 32768) {                          // enc1: W1 [256,128], CT=8
        int l = tt;
        int j = l & 7, lane = (l >> 3) & 63, ct = (l >> 9) & 7, kk = l >> 12;
        int k = kk * 32 + ((lane >> 4) << 3) + j, c = (ct << 4) + (lane & 15);
        v = W1[k * 128 + c];
    } else if (tt < 49152) {                   // enc2: W2 [128,128], CT=8
        int l = tt - 32768;
        int j = l & 7, lane = (l >> 3) & 63, ct = (l >> 9) & 7, kk = l >> 12;
        int k = kk * 32 + ((lane >> 4) << 3) + j, c = (ct << 4) + (lane & 15);
        v = W2[k * 128 + c];
    } else if (tt < 81920) {                   // conv1: [Wrel1;Wroot1] K=256, CT=8
        int l = tt - 49152;
        int j = l & 7, lane = (l >> 3) & 63, ct = (l >> 9) & 7, kk = l >> 12;
        int k = kk * 32 + ((lane >> 4) << 3) + j, c = (ct << 4) + (lane & 15);
        v = (k < 128) ? Wrel1[k * 128 + c] : Wroot1[(k - 128) * 128 + c];
    } else if (tt < 114688) {                  // conv2
        int l = tt - 81920;
        int j = l & 7, lane = (l >> 3) & 63, ct = (l >> 9) & 7, kk = l >> 12;
        int k = kk * 32 + ((lane >> 4) << 3) + j, c = (ct << 4) + (lane & 15);
        v = (k < 128) ? Wrel2[k * 128 + c] : Wroot2[(k - 128) * 128 + c];
    } else if (tt < 118784) {                  // dec1: Wd1 [32,128], CT=8, kk=0
        int l = tt - 114688;
        int j = l & 7, lane = (l >> 3) & 63, ct = (l >> 9) & 7;
        int k = ((lane >> 4) << 3) + j, c = (ct << 4) + (lane & 15);
        v = Wd1[k * 128 + c];
    } else if (tt < 151552) {                  // dec2: Wd2 [128,256], CT=16
        int l = tt - 118784;
        int j = l & 7, lane = (l >> 3) & 63, ct = (l >> 9) & 15, kk = l >> 13;
        int k = kk * 32 + ((lane >> 4) << 3) + j, c = (ct << 4) + (lane & 15);
        v = Wd2[k * 256 + c];
    } else {                                  // heads: [Wmu|Wlv] [128,64], CT=4
        int l = tt - 151552;
        int j = l & 7, lane = (l >> 3) & 63, ct = (l >> 9) & 3, kk = l >> 11;
        int k = kk * 32 + ((lane >> 4) << 3) + j, c = (ct << 4) + (lane & 15);
        v = (c < 32) ? Wmu[k * 32 + c] : Wlv[k * 32 + (c - 32)];
    }
    pack[tt] = (f16)v;
}

// ---------------------------------------------------------------------------
// MFMA GEMM building blocks. 64 nodes/block, 4 waves, wave = 16 nodes.
// ---------------------------------------------------------------------------
template<int C>
__device__ __forceinline__ void stage_tile(const float* __restrict__ src, int nbase,
                                           f16* lds, int ldr, int colofs)
{
    const int t = threadIdx.x;
    #pragma unroll
    for (int i = 0; i < (64 * C / 4) / 256; i++) {
        int elem = t + i * 256;
        int row = elem / (C / 4);
        int c4  = elem % (C / 4);
        int srow = nbase + row; if (srow >= NN) srow = NN - 1;
        float4 v = *(const float4*)(src + (size_t)srow * C + c4 * 4);
        union { f16 h[4]; uint2 u; } cv;
        cv.h[0] = (f16)v.x; cv.h[1] = (f16)v.y; cv.h[2] = (f16)v.z; cv.h[3] = (f16)v.w;
        *(uint2*)&lds[row * ldr + colofs + c4 * 4] = cv.u;
    }
}

template<int C>
__device__ __forceinline__ void stage_tile_f16(const f16* __restrict__ src, int nbase,
                                               f16* lds, int ldr, int colofs)
{
    const int t = threadIdx.x;
    #pragma unroll
    for (int i = 0; i < (64 * C / 4) / 256; i++) {
        int elem = t + i * 256;
        int row = elem / (C / 4);
        int c4  = elem % (C / 4);
        int srow = nbase + row; if (srow >= NN) srow = NN - 1;
        uint2 v = *(const uint2*)(src + (size_t)srow * C + c4 * 4);
        *(uint2*)&lds[row * ldr + colofs + c4 * 4] = v;
    }
}

template<int K, int CT>
__device__ __forceinline__ void wave_gemm(const f16* lds, int ldr,
                                          const f16x8* __restrict__ wp, f32x4 acc[CT])
{
    const int lane = threadIdx.x & 63;
    const int wrow = (threadIdx.x >> 6) * 16;
    const int arow = wrow + (lane & 15);
    const int kofs = (lane >> 4) << 3;
    #pragma unroll
    for (int kk = 0; kk < K / 32; kk++) {
        f16x8 a = *(const f16x8*)&lds[arow * ldr + kk * 32 + kofs];
        #pragma unroll
        for (int ct = 0; ct < CT; ct++) {
            f16x8 b = wp[(kk * CT + ct) * 64 + lane];
            acc[ct] = mfma16(a, b, acc[ct]);
        }
    }
}

template<int CT>
__device__ __forceinline__ void zacc(f32x4 acc[CT])
{
    #pragma unroll
    for (int ct = 0; ct < CT; ct++) acc[ct] = f32x4{0.f, 0.f, 0.f, 0.f};
}

// C/D layout (m89): col = lane&15, row = (lane>>4)*4 + reg
template<int CT, bool RELU>
__device__ __forceinline__ void store_f32(float* __restrict__ dst, int OUTC, int nbase,
                                          const float* __restrict__ bias, f32x4 acc[CT])
{
    const int lane = threadIdx.x & 63;
    const int wrow = (threadIdx.x >> 6) * 16;
    #pragma unroll
    for (int ct = 0; ct < CT; ct++) {
        int c = ct * 16 + (lane & 15);
        float bv = bias[c];
        #pragma unroll
        for (int r = 0; r < 4; r++) {
            int node = nbase + wrow + ((lane >> 4) << 2) + r;
            if (node < NN) {
                float v = acc[ct][r] + bv;
                if (RELU) v = frelu(v);
                dst[(size_t)node * OUTC + c] = v;
            }
        }
    }
}

template<int CT, bool RELU>
__device__ __forceinline__ void store_f16g(f16* __restrict__ dst, int OUTC, int nbase,
                                           const float* __restrict__ bias, f32x4 acc[CT])
{
    const int lane = threadIdx.x & 63;
    const int wrow = (threadIdx.x >> 6) * 16;
    #pragma unroll
    for (int ct = 0; ct < CT; ct++) {
        int c = ct * 16 + (lane & 15);
        float bv = bias[c];
        #pragma unroll
        for (int r = 0; r < 4; r++) {
            int node = nbase + wrow + ((lane >> 4) << 2) + r;
            if (node < NN) {
                float v = acc[ct][r] + bv;
                if (RELU) v = frelu(v);
                dst[(size_t)node * OUTC + c] = (f16)v;
            }
        }
    }
}

template<int CT>
__device__ __forceinline__ void store_lds_f16(f16* lds, int ldr,
                                              const float* __restrict__ bias, f32x4 acc[CT])
{
    const int lane = threadIdx.x & 63;
    const int wrow = (threadIdx.x >> 6) * 16;
    #pragma unroll
    for (int ct = 0; ct < CT; ct++) {
        int c = ct * 16 + (lane & 15);
        float bv = bias[c];
        #pragma unroll
        for (int r = 0; r < 4; r++) {
            int row = wrow + ((lane >> 4) << 2) + r;
            lds[row * ldr + c] = (f16)frelu(acc[ct][r] + bv);
        }
    }
}

// ---------------------------------------------------------------------------
// colscan_enc: blocks 0..NCB-1 = colscan, 16 buckets per block with COALESCED
// blockhist IO (R21 profile: per-bucket column reads were 16x line-amplified
// and ran at 3 blocks/CU under the 50KB LDS). Two-level scan in LDS, stride
// 17 padding. blocks NCB.. = encoder tiles (unchanged).
// ---------------------------------------------------------------------------
__global__ __launch_bounds__(256) void colscan_enc(int* __restrict__ blockhist,
                                                   int* __restrict__ totals,
                                                   const float* __restrict__ x,
                                                   const f16x8* __restrict__ wp1,
                                                   const f16x8* __restrict__ wp2,
                                                   const float* __restrict__ b1,
                                                   const float* __restrict__ b2,
                                                   f16* __restrict__ out)
{
    __shared__ __align__(16) f16 shbuf[64 * 264 + 64 * 136];
    const int t = threadIdx.x;
    if (blockIdx.x < NCB) {
        int* hsI  = (int*)shbuf;                 // [250][17] ints
        int* segS = hsI + 250 * 17;              // [16][17] ints
        const int k0 = blockIdx.x * 16;
        // coalesced load: 16 consecutive buckets per row = one 64B line
        for (int idx = t; idx < 250 * 16; idx += 256) {
            int row = idx >> 4, col = idx & 15;
            int k = k0 + col;
            hsI[row * 17 + col] = (k < NB) ? blockhist[row * NB + k] : 0;
        }
        __syncthreads();
        const int col = t & 15, seg = t >> 4;
        const int r0 = seg * 16;
        const int r1 = (r0 + 16 < 250) ? r0 + 16 : 250;
        int s = 0;
        for (int r = r0; r < r1; r++) s += hsI[r * 17 + col];
        segS[seg * 17 + col] = s;
        __syncthreads();
        if (t < 16) {
            int run = 0;
            #pragma unroll
            for (int g = 0; g < 16; g++) {
                int tmp = segS[g * 17 + t];
                segS[g * 17 + t] = run;
                run += tmp;
            }
            if (k0 + t < NB) totals[k0 + t] = run;
        }
        __syncthreads();
        int run = segS[seg * 17 + col];
        for (int r = r0; r < r1; r++) {
            int old = hsI[r * 17 + col];
            hsI[r * 17 + col] = run;
            run += old;
        }
        __syncthreads();
        for (int idx = t; idx < 250 * 16; idx += 256) {
            int row = idx >> 4, col2 = idx & 15;
            int k = k0 + col2;
            if (k < NB) blockhist[row * NB + k] = hsI[row * 17 + col2];
        }
        return;
    }
    // encoder tile
    f16* xs = shbuf;                 // [64*264]
    f16* h1 = shbuf + 64 * 264;      // [64*136]
    const int nbase = (blockIdx.x - NCB) * 64;
    stage_tile<256>(x, nbase, xs, 264, 0);
    __syncthreads();
    f32x4 acc[8];
    zacc<8>(acc);
    wave_gemm<256, 8>(xs, 264, wp1, acc);
    store_lds_f16<8>(h1, 136, b1, acc);
    __syncthreads();
    zacc<8>(acc);
    wave_gemm<128, 8>(h1, 136, wp2, acc);
    store_f16g<8, true>(out, 128, nbase, b2, acc);
}

// ---------------------------------------------------------------------------
// scatter: per-(block,bucket) CONTIGUOUS runs into tmp (R12-verified).
// Record: {src | local<<17, weight_bits}, local = dst & 63.
// ---------------------------------------------------------------------------
__global__ __launch_bounds__(256) void scatter(const int* __restrict__ src,
                                               const int* __restrict__ dst,
                                               const float* __restrict__ ea,
                                               const int* __restrict__ totals,
                                               const int* __restrict__ blockhist,
                                               int* __restrict__ bs_g,
                                               int2* __restrict__ tmp)
{
    __shared__ int bsS[NB + 1];
    __shared__ int tmpS[256];
    __shared__ int carryS;
    __shared__ int prefS[NB];
    __shared__ int cntS[NB];
    const int t = threadIdx.x, blk = blockIdx.x;
    if (t == 0) carryS = 0;
    __syncthreads();
    for (int c = 0; c < 7; c++) {
        int idx = c * 256 + t;
        int val = (idx < NB) ? totals[idx] : 0;
        tmpS[t] = val;
        __syncthreads();
        for (int off = 1; off < 256; off <<= 1) {
            int y = (t >= off) ? tmpS[t - off] : 0;
            __syncthreads();
            tmpS[t] += y;
            __syncthreads();
        }
        if (idx < NB) bsS[idx] = carryS + tmpS[t] - val;
        __syncthreads();
        if (t == 255) carryS += tmpS[255];
        __syncthreads();
    }
    if (t == 0) bsS[NB] = carryS;    // == EE
    for (int i = t; i < NB; i += 256) {
        prefS[i] = blockhist[blk * NB + i];
        cntS[i] = 0;
    }
    __syncthreads();
    if (blk == 0)
        for (int i = t; i < NB + 1; i += 256) bs_g[i] = bsS[i];
    const int ebase = blk * 6400;
    #pragma unroll
    for (int i = 0; i < 25; i++) {
        int e = ebase + i * 256 + t;
        int d = dst[e];
        int k = d >> 6;
        int rank = atomicAdd(&cntS[k], 1);
        int pos = bsS[k] + prefS[k] + rank;
        tmp[pos] = make_int2(src[e] | ((d & 63) << 17), __float_as_int(ea[e]));
    }
}

// ---------------------------------------------------------------------------
// bucket_sort: per-bucket 64-bin counting sort; emits offsets/counts (R12).
// ---------------------------------------------------------------------------
__global__ __launch_bounds__(256) void bucket_sort(const int2* __restrict__ tmp,
                                                   const int* __restrict__ bs_g,
                                                   int2* __restrict__ pairs,
                                                   int* __restrict__ offsets,
                                                   int* __restrict__ counts)
{
    __shared__ int hist[64], excl[64], cursor[64];
    const int t = threadIdx.x, k = blockIdx.x;
    const int start = bs_g[k], end = bs_g[k + 1];
    if (t < 64) hist[t] = 0;
    __syncthreads();
    for (int i = start + t; i < end; i += 256)
        atomicAdd(&hist[(tmp[i].x >> 17) & 63], 1);
    __syncthreads();
    if (t == 0) {
        int run = 0;
        #pragma unroll
        for (int j = 0; j < 64; j++) { excl[j] = run; cursor[j] = run; run += hist[j]; }
    }
    __syncthreads();
    for (int i = start + t; i < end; i += 256) {
        int2 e = tmp[i];
        int local = (e.x >> 17) & 63;
        int rank = atomicAdd(&cursor[local], 1);
        pairs[start + rank] = make_int2(e.x & 0x1FFFF, e.y);
    }
    if (t < 64) {
        int node = (k << 6) + t;
        if (node < NN) {
            counts[node]  = hist[t];
            offsets[node] = start + excl[t] + hist[t];   // END semantics
        }
    }
}

// ---------------------------------------------------------------------------
// Aggregation: quarter-wave (16 lanes x 16B) per node, unroll 8 (R21: 386us).
// ---------------------------------------------------------------------------
__global__ __launch_bounds__(256) void agg_q(const f16* __restrict__ h,
                                             const int2* __restrict__ pairs,
                                             const int* __restrict__ offsets,
                                             const int* __restrict__ counts,
                                             f16* __restrict__ out)
{
    const int gt   = blockIdx.x * 256 + threadIdx.x;   // grid exact: 6250*256
    const int node = gt >> 4;                          // 100000 nodes
    const int ch   = gt & 15;                          // 16B chunk within row
    const int end  = offsets[node];
    int i = end - counts[node];
    float acc[8];
    #pragma unroll
    for (int j = 0; j < 8; j++) acc[j] = 0.f;
    const uint4* __restrict__ h16 = (const uint4*)h;   // 16 chunks per row
    for (; i + 8 <= end; i += 8) {
        int2 p[8];
        uint4 r[8];
        #pragma unroll
        for (int u = 0; u < 8; u++) p[u] = nt_load_int2(pairs + i + u);
        #pragma unroll
        for (int u = 0; u < 8; u++) r[u] = h16[(size_t)p[u].x * 16 + ch];
        #pragma unroll
        for (int u = 0; u < 8; u++) {
            float w = __int_as_float(p[u].y);
            const f16* e = (const f16*)&r[u];
            #pragma unroll
            for (int j = 0; j < 8; j++) acc[j] = fmaf(w, (float)e[j], acc[j]);
        }
    }
    for (; i + 4 <= end; i += 4) {
        int2 p0 = nt_load_int2(pairs + i);
        int2 p1 = nt_load_int2(pairs + i + 1);
        int2 p2 = nt_load_int2(pairs + i + 2);
        int2 p3 = nt_load_int2(pairs + i + 3);
        uint4 r0 = h16[(size_t)p0.x * 16 + ch];
        uint4 r1 = h16[(size_t)p1.x * 16 + ch];
        uint4 r2 = h16[(size_t)p2.x * 16 + ch];
        uint4 r3 = h16[(size_t)p3.x * 16 + ch];
        float w0 = __int_as_float(p0.y), w1 = __int_as_float(p1.y);
        float w2 = __int_as_float(p2.y), w3 = __int_as_float(p3.y);
        const f16* e0 = (const f16*)&r0;
        const f16* e1 = (const f16*)&r1;
        const f16* e2 = (const f16*)&r2;
        const f16* e3 = (const f16*)&r3;
        #pragma unroll
        for (int j = 0; j < 8; j++) acc[j] = fmaf(w0, (float)e0[j], acc[j]);
        #pragma unroll
        for (int j = 0; j < 8; j++) acc[j] = fmaf(w1, (float)e1[j], acc[j]);
        #pragma unroll
        for (int j = 0; j < 8; j++) acc[j] = fmaf(w2, (float)e2[j], acc[j]);
        #pragma unroll
        for (int j = 0; j < 8; j++) acc[j] = fmaf(w3, (float)e3[j], acc[j]);
    }
    for (; i < end; ++i) {
        int2 p0 = nt_load_int2(pairs + i);
        uint4 r0 = h16[(size_t)p0.x * 16 + ch];
        float w0 = __int_as_float(p0.y);
        const f16* e0 = (const f16*)&r0;
        #pragma unroll
        for (int j = 0; j < 8; j++) acc[j] = fmaf(w0, (float)e0[j], acc[j]);
    }
    union { f16 hh[8]; uint4 u; } cv;
    #pragma unroll
    for (int j = 0; j < 8; j++) cv.hh[j] = (f16)acc[j];
    ((uint4*)out)[(size_t)node * 16 + ch] = cv.u;
}

// ---------------------------------------------------------------------------
// GraphConv combine: out = relu([agg|h]@[Wrel;Wroot]+brel), fp16 in/out.
// ---------------------------------------------------------------------------
__global__ __launch_bounds__(256) void conv_mfma(const f16* __restrict__ agg,
                                                 const f16* __restrict__ h,
                                                 const f16x8* __restrict__ wp,
                                                 const float* __restrict__ brel,
                                                 f16* __restrict__ out)
{
    __shared__ __align__(16) f16 as_[64 * 264];
    const int nbase = blockIdx.x * 64;
    stage_tile_f16<128>(agg, nbase, as_, 264, 0);
    stage_tile_f16<128>(h,   nbase, as_, 264, 128);
    __syncthreads();
    f32x4 acc[8];
    zacc<8>(acc);
    wave_gemm<256, 8>(as_, 264, wp, acc);
    store_f16g<8, true>(out, 128, nbase, brel, acc);
}

// ---------------------------------------------------------------------------
// tail2_mfma: heads (MFMA CT=4) + reparam + decoder, LDS-chained (R19, 397us).
// ---------------------------------------------------------------------------
__global__ __launch_bounds__(256) void tail2_mfma(const f16* __restrict__ h,
                                                  const f16x8* __restrict__ wp_hd,
                                                  const float* __restrict__ bmu,
                                                  const float* __restrict__ blv,
                                                  const f16x8* __restrict__ wp_d1,
                                                  const float* __restrict__ bd1,
                                                  const f16x8* __restrict__ wp_d2,
                                                  const float* __restrict__ bd2,
                                                  const float* __restrict__ eps,
                                                  float* __restrict__ out)
{
    __shared__ __align__(16) f16 hsA[64 * 136];     // h staging, reused as hd
    __shared__ __align__(16) float muS[64 * 32];
    __shared__ __align__(16) float lvS[64 * 32];
    __shared__ __align__(16) f16 zf[64 * 40];
    const int nbase = blockIdx.x * 64;
    const int t = threadIdx.x;
    const int lane = t & 63;
    const int wrow = (t >> 6) * 16;

    stage_tile_f16<128>(h, nbase, hsA, 136, 0);
    __syncthreads();

    // --- heads ---
    f32x4 acc4[4];
    zacc<4>(acc4);
    wave_gemm<128, 4>(hsA, 136, wp_hd, acc4);
    #pragma unroll
    for (int ct = 0; ct < 4; ct++) {
        int c = ct * 16 + (lane & 15);
        bool ismu = (c < 32);
        int cc = c & 31;
        float bv = ismu ? bmu[cc] : blv[cc];
        float* gbase = out + (ismu ? (size_t)25600000 : (size_t)28800000);
        float* sb = ismu ? muS : lvS;
        #pragma unroll
        for (int r = 0; r < 4; r++) {
            int row = wrow + ((lane >> 4) << 2) + r;
            int node = nbase + row;
            float v = acc4[ct][r] + bv;
            sb[row * 32 + cc] = v;
            if (node < NN) gbase[(size_t)node * 32 + cc] = v;
        }
    }
    __syncthreads();

    // --- reparam ---
    {
        const int node = t >> 2;             // 0..63
        const int ch0  = (t & 3) * 8;        // 0,8,16,24
        const int gn = nbase + node;
        const float* mu = &muS[node * 32 + ch0];
        const float* lv = &lvS[node * 32 + ch0];
        float4 e0 = make_float4(0.f, 0.f, 0.f, 0.f), e1 = e0;
        if (gn < NN) {
            const size_t g = (size_t)gn * 32 + ch0;
            e0 = *(const float4*)(eps + g);
            e1 = *(const float4*)(eps + g + 4);
        }
        float zv[8];
        zv[0] = fmaf(e0.x, expf(0.5f * lv[0]), mu[0]);
        zv[1] = fmaf(e0.y, expf(0.5f * lv[1]), mu[1]);
        zv[2] = fmaf(e0.z, expf(0.5f * lv[2]), mu[2]);
        zv[3] = fmaf(e0.w, expf(0.5f * lv[3]), mu[3]);
        zv[4] = fmaf(e1.x, expf(0.5f * lv[4]), mu[4]);
        zv[5] = fmaf(e1.y, expf(0.5f * lv[5]), mu[5]);
        zv[6] = fmaf(e1.z, expf(0.5f * lv[6]), mu[6]);
        zv[7] = fmaf(e1.w, expf(0.5f * lv[7]), mu[7]);
        if (gn < NN) {
            const size_t g = (size_t)gn * 32 + ch0;
            *(float4*)(out + 32000000 + g)     = make_float4(zv[0], zv[1], zv[2], zv[3]);
            *(float4*)(out + 32000000 + g + 4) = make_float4(zv[4], zv[5], zv[6], zv[7]);
        }
        #pragma unroll
        for (int j = 0; j < 8; j++) zf[node * 40 + ch0 + j] = (f16)zv[j];
    }
    __syncthreads();

    // --- dec1 ---
    f32x4 acc8[8];
    zacc<8>(acc8);
    wave_gemm<32, 8>(zf, 40, wp_d1, acc8);
    store_lds_f16<8>(hsA, 136, bd1, acc8);
    __syncthreads();

    // --- dec2 ---
    f32x4 acc16[16];
    zacc<16>(acc16);
    wave_gemm<128, 16>(hsA, 136, wp_d2, acc16);
    store_f32<16, false>(out, 256, nbase, bd2, acc16);
}

// ---------------------------------------------------------------------------
extern "C" void kernel_launch(void* const* d_in, const int* in_sizes, int n_in,
                              void* d_out, int out_size, void* d_ws, size_t ws_size,
                              hipStream_t stream)
{
    const float* x     = (const float*)d_in[0];
    const int*   ei    = (const int*)d_in[1];
    const float* ea    = (const float*)d_in[2];
    const float* W1    = (const float*)d_in[3];
    const float* b1    = (const float*)d_in[4];
    const float* W2    = (const float*)d_in[5];
    const float* b2    = (const float*)d_in[6];
    const float* Wrel1 = (const float*)d_in[7];
    const float* brel1 = (const float*)d_in[8];
    const float* Wroot1= (const float*)d_in[9];
    const float* Wrel2 = (const float*)d_in[10];
    const float* brel2 = (const float*)d_in[11];
    const float* Wroot2= (const float*)d_in[12];
    const float* Wmu   = (const float*)d_in[13];
    const float* bmu   = (const float*)d_in[14];
    const float* Wlv   = (const float*)d_in[15];
    const float* blv   = (const float*)d_in[16];
    const float* Wd1   = (const float*)d_in[17];
    const float* bd1   = (const float*)d_in[18];
    const float* Wd2   = (const float*)d_in[19];
    const float* bd2   = (const float*)d_in[20];
    const float* eps   = (const float*)d_in[21];
    float* out = (float*)d_out;

    char* ws = (char*)d_ws;
    int*  totals    = (int*) (ws);                  // [NB]  (pad to 8 KB)
    int*  blockhist = (int*) (ws + 8192);           // [250*NB]     1.56 MB
    int*  bs_g      = (int*) (ws + 1571200);        // [NB+1]
    int2* tmp       = (int2*)(ws + 1577472);        // [E]          12.8 MB
    int2* pairs     = (int2*)(ws + 14377472);       // [E]          12.8 MB
    int*  offsets   = (int*) (ws + 27177472);       // [N]          400 KB
    int*  counts    = (int*) (ws + 27577472);       // [N]          400 KB
    f16*  pack      = (f16*) (ws + 27977472);       // 159744 halves ~319 KB
    // 256B-aligned h buffers (R14/R17 lesson).
    f16*  B0        = (f16*) (ws + 28311552);       // 28311552 = 110592*256
    f16*  B1        = (f16*) (ws + 53911552);       // 53911552 = 210592*256

    const f16x8* wp_enc1  = (const f16x8*)(pack);
    const f16x8* wp_enc2  = (const f16x8*)(pack + 32768);
    const f16x8* wp_conv1 = (const f16x8*)(pack + 49152);
    const f16x8* wp_conv2 = (const f16x8*)(pack + 81920);
    const f16x8* wp_dec1  = (const f16x8*)(pack + 114688);
    const f16x8* wp_dec2  = (const f16x8*)(pack + 118784);
    const f16x8* wp_heads = (const f16x8*)(pack + 151552);

    const int* src = ei;          // edge_index row 0
    const int* dst = ei + EE;     // edge_index row 1

    // --- CSR build + weight packing + encoder (enc hides under colscan) ---
    hist_pack<<<874, 256, 0, stream>>>(dst, blockhist, W1, W2, Wrel1, Wroot1,
                                       Wrel2, Wroot2, Wd1, Wd2, Wmu, Wlv, pack);
    colscan_enc<<<NCB + 1563, 256, 0, stream>>>(blockhist, totals, x,
                                                wp_enc1, wp_enc2, b1, b2, B0);
    scatter<<<250, 256, 0, stream>>>(src, dst, ea, totals, blockhist, bs_g, tmp);
    bucket_sort<<<NB, 256, 0, stream>>>(tmp, bs_g, pairs, offsets, counts);

    // --- forward pass: 8 dispatches total ---
    agg_q<<<6250, 256, 0, stream>>>(B0, pairs, offsets, counts, B1);
    conv_mfma<<<1563, 256, 0, stream>>>(B1, B0, wp_conv1, brel1, B1);
    agg_q<<<6250, 256, 0, stream>>>(B1, pairs, offsets, counts, B0);
    conv_mfma<<<1563, 256, 0, stream>>>(B0, B1, wp_conv2, brel2, B0);
    tail2_mfma<<<1563, 256, 0, stream>>>(B0, wp_heads, bmu, blv,
                                         wp_dec1, bd1, wp_dec2, bd2, eps, out);
}